// Round 5
// baseline (479.231 us; speedup 1.0000x reference)
//
#include <hip/hip_runtime.h>

#define RR 32
#define R3 32768
#define BATCH 8
#define CH 64
#define NPTS 100000
#define NPOINTS (BATCH * NPTS)   // 800000
#define NVOX (BATCH * R3)        // 262144
#define SCAN_BLOCKS (NVOX / 256) // 1024
#define HBLK 8                   // histogram blocks per batch
#define PPB (NPTS / HBLK)        // 12500 points per hist block (rank < 2^14)

typedef unsigned int uint32;

__device__ __forceinline__ uint32 f2bf(float f) {
    uint32 u = __float_as_uint(f);
    return (u + 0x7fffu + ((u >> 16) & 1u)) >> 16;   // RNE to bf16
}
__device__ __forceinline__ float bf2f(uint32 h) {
    return __uint_as_float(h << 16);
}

// ---------------------------------------------------------------------------
// K1 (primary): voxelize + LDS hist; the ds-atomic RETURN is the point's
// stable local rank. vox[gid] = v | (rank << 16). Partial counts -> phist.
// ---------------------------------------------------------------------------
__global__ __launch_bounds__(256) void voxrank(
    const float* __restrict__ coords,  // [B, 3, N]
    uint32* __restrict__ vox,          // [NPOINTS] packed v | rank<<16
    uint32* __restrict__ phist,        // [B*HBLK][R3] partial histograms
    float* __restrict__ out2)          // [B, 3, N] voxel coords as float
{
    __shared__ uint32 hist[R3];        // 128 KiB

    int b   = blockIdx.x >> 3;         // 0..7
    int blk = blockIdx.x & 7;          // 0..7
    int tid = threadIdx.x;

    uint4 z4 = make_uint4(0u, 0u, 0u, 0u);
    for (int i = tid; i < R3 / 4; i += 256) ((uint4*)hist)[i] = z4;
    __syncthreads();

    int n0 = blk * PPB;
    const float* cb = coords + (size_t)b * 3 * NPTS;
    float*       o2 = out2   + (size_t)b * 3 * NPTS;

    for (int i = tid; i < PPB; i += 256) {
        int n = n0 + i;
        float fx = fminf(fmaxf(cb[n]            * 32.0f, 0.0f), 31.0f);
        float fy = fminf(fmaxf(cb[NPTS + n]     * 32.0f, 0.0f), 31.0f);
        float fz = fminf(fmaxf(cb[2 * NPTS + n] * 32.0f, 0.0f), 31.0f);
        int x = (int)rintf(fx);   // round-half-even matches jnp.round
        int y = (int)rintf(fy);
        int z = (int)rintf(fz);
        int v = x * (RR * RR) + y * RR + z;

        o2[n]            = (float)x;
        o2[NPTS + n]     = (float)y;
        o2[2 * NPTS + n] = (float)z;

        uint32 r = atomicAdd(&hist[v], 1u);           // ds_add_rtn, local rank
        vox[(size_t)b * NPTS + n] = (uint32)v | (r << 16);
    }
    __syncthreads();

    uint4* ph = (uint4*)(phist + (size_t)(b * HBLK + blk) * R3);
    for (int i = tid; i < R3 / 4; i += 256) ph[i] = ((const uint4*)hist)[i];
}

// ---------------------------------------------------------------------------
// K2: sum the HBLK partial histograms per voxel -> cnt, plus block sums.
// ---------------------------------------------------------------------------
__global__ __launch_bounds__(256) void scan_hist_sums(
    const uint32* __restrict__ phist,
    uint32* __restrict__ cnt, uint32* __restrict__ bsum)
{
    __shared__ uint32 s[256];
    int t = threadIdx.x;
    int gid = blockIdx.x * 256 + t;
    int b = gid >> 15;                 // gid / R3
    int v = gid & (R3 - 1);

    const uint32* ph = phist + (size_t)b * HBLK * R3 + v;
    uint32 c = 0;
#pragma unroll
    for (int k = 0; k < HBLK; ++k) c += ph[(size_t)k * R3];
    cnt[gid] = c;

    s[t] = c;
    __syncthreads();
    for (int off = 128; off > 0; off >>= 1) {
        if (t < off) s[t] += s[t + off];
        __syncthreads();
    }
    if (t == 0) bsum[blockIdx.x] = s[0];
}

// ---------------------------------------------------------------------------
// K3: scan over the 1024 block sums (single block).
// ---------------------------------------------------------------------------
__global__ __launch_bounds__(256) void scan_bsum(uint32* __restrict__ bsum)
{
    __shared__ uint32 s[256];
    int t = threadIdx.x;
    uint32 v0 = bsum[4 * t], v1 = bsum[4 * t + 1], v2 = bsum[4 * t + 2], v3 = bsum[4 * t + 3];
    uint32 tot = v0 + v1 + v2 + v3;
    s[t] = tot;
    __syncthreads();
    for (int off = 1; off < 256; off <<= 1) {
        uint32 x = (t >= off) ? s[t - off] : 0u;
        __syncthreads();
        s[t] += x;
        __syncthreads();
    }
    uint32 excl = s[t] - tot;
    bsum[4 * t]     = excl;
    bsum[4 * t + 1] = excl + v0;
    bsum[4 * t + 2] = excl + v0 + v1;
    bsum[4 * t + 3] = excl + v0 + v1 + v2;
}

// ---------------------------------------------------------------------------
// K4 (primary): exclusive scan -> starts only (no cursor; scatter is
// atomic-free).
// ---------------------------------------------------------------------------
__global__ __launch_bounds__(256) void scan_starts(
    const uint32* __restrict__ cnt, const uint32* __restrict__ bsum,
    uint32* __restrict__ starts)
{
    __shared__ uint32 s[256];
    int t = threadIdx.x;
    int gid = blockIdx.x * 256 + t;
    uint32 v = cnt[gid];
    s[t] = v;
    __syncthreads();
    for (int off = 1; off < 256; off <<= 1) {
        uint32 x = (t >= off) ? s[t - off] : 0u;
        __syncthreads();
        s[t] += x;
        __syncthreads();
    }
    starts[gid] = bsum[blockIdx.x] + s[t] - v;   // exclusive
}

// ---------------------------------------------------------------------------
// K5 (primary): turn partial counts into per-(block,voxel) BASES, in place:
// pbase[b][k][v] = starts[b*R3+v] + sum_{j<k} phist[b][j][v]
// ---------------------------------------------------------------------------
__global__ __launch_bounds__(256) void make_pbase(
    uint32* __restrict__ phist,        // in: counts, out: bases
    const uint32* __restrict__ starts)
{
    int gid = blockIdx.x * 256 + threadIdx.x;   // over NVOX
    int b = gid >> 15;
    int v = gid & (R3 - 1);
    uint32 s = starts[gid];
    uint32* ph = phist + (size_t)b * HBLK * R3 + v;
#pragma unroll
    for (int k = 0; k < HBLK; ++k) {
        uint32 c = ph[(size_t)k * R3];
        ph[(size_t)k * R3] = s;
        s += c;
    }
}

// ---------------------------------------------------------------------------
// K6 (primary): ATOMIC-FREE scatter. pos = pbase[blk][v] + rank.
// pbase is read-only -> lines replicate across XCD L2s, no RMW ping-pong.
// ---------------------------------------------------------------------------
__global__ __launch_bounds__(256) void scatter_rank(
    const float* __restrict__ feat,    // [B, C, N]
    const uint32* __restrict__ vox,    // packed v | rank<<16
    const uint32* __restrict__ pbase,  // [B*HBLK][R3] bases
    uint4* __restrict__ sorted)        // [NPOINTS][8] uint4 (= 64 bf16 ch)
{
    int gid = blockIdx.x * blockDim.x + threadIdx.x;
    if (gid >= NPOINTS) return;
    int b = gid / NPTS;
    int n = gid - b * NPTS;

    uint32 vr = vox[gid];
    uint32 v  = vr & 0xffffu;
    uint32 r  = vr >> 16;
    int   blk = n / PPB;               // 0..7
    uint32 pos = pbase[(size_t)(b * HBLK + blk) * R3 + v] + r;

    const float* frow = feat + (size_t)b * CH * NPTS + n;
    uint4* dst = sorted + (size_t)pos * 8;
#pragma unroll
    for (int j = 0; j < 8; ++j) {
        uint4 w;
        float f0 = frow[(size_t)(8 * j + 0) * NPTS];
        float f1 = frow[(size_t)(8 * j + 1) * NPTS];
        float f2 = frow[(size_t)(8 * j + 2) * NPTS];
        float f3 = frow[(size_t)(8 * j + 3) * NPTS];
        float f4 = frow[(size_t)(8 * j + 4) * NPTS];
        float f5 = frow[(size_t)(8 * j + 5) * NPTS];
        float f6 = frow[(size_t)(8 * j + 6) * NPTS];
        float f7 = frow[(size_t)(8 * j + 7) * NPTS];
        w.x = f2bf(f0) | (f2bf(f1) << 16);
        w.y = f2bf(f2) | (f2bf(f3) << 16);
        w.z = f2bf(f4) | (f2bf(f5) << 16);
        w.w = f2bf(f6) | (f2bf(f7) << 16);
        dst[j] = w;
    }
}

// ---------------------------------------------------------------------------
// K7: per-block reduce of 64 consecutive voxels, FULL-wave (R3-verified).
// ---------------------------------------------------------------------------
__global__ __launch_bounds__(256) void phase4_reduce(
    const uint32* __restrict__ sorted,   // [NPOINTS][32] uint (bf16x2)
    const uint32* __restrict__ starts,
    float* __restrict__ out1)            // [B, C, R3]
{
    __shared__ float tile[64][65];

    int gbase = blockIdx.x * 64;       // global voxel base
    int tid = threadIdx.x;
    int w = tid >> 6, lane = tid & 63;
    int half = lane >> 5;              // 0: even points, 1: odd points
    int cp   = lane & 31;              // channel-pair index

    for (int k = 0; k < 16; ++k) {
        int g = gbase + w * 16 + k;
        uint32 s = starts[g];
        uint32 e = (g == NVOX - 1) ? (uint32)NPOINTS : starts[g + 1];
        float a0 = 0.0f, a1 = 0.0f;
        for (uint32 p = s + half; p < e; p += 2) {
            uint32 d = sorted[(size_t)p * 32 + cp];
            a0 += bf2f(d & 0xffffu);
            a1 += bf2f(d >> 16);
        }
        a0 += __shfl_xor(a0, 32);
        a1 += __shfl_xor(a1, 32);
        if (half == 0) {
            uint32 c = e - s;
            float rcp = 1.0f / (float)(c > 1u ? c : 1u);
            int vloc = w * 16 + k;
            tile[vloc][2 * cp]     = a0 * rcp;
            tile[vloc][2 * cp + 1] = a1 * rcp;
        }
    }
    __syncthreads();

    int b = gbase / R3;
    int v0 = gbase - b * R3;
    int vv = tid & 63;
    int c0 = tid >> 6;
    float* obase = out1 + (size_t)b * CH * R3 + v0 + vv;
#pragma unroll
    for (int jj = 0; jj < 16; ++jj) {
        int c = jj * 4 + c0;
        obase[(size_t)c * R3] = tile[vv][c];
    }
}

// ---------------------------------------------------------------------------
// Middle path (ws fits R0 layout but not phist): R0-proven cursor pipeline.
// ---------------------------------------------------------------------------
__global__ __launch_bounds__(256) void phase1_count(
    const float* __restrict__ coords,
    uint32* __restrict__ vox,          // GLOBAL voxel id
    uint32* __restrict__ cnt,          // pre-zeroed
    float* __restrict__ out2)
{
    int gid = blockIdx.x * blockDim.x + threadIdx.x;
    if (gid >= NPOINTS) return;
    int b = gid / NPTS;
    int n = gid - b * NPTS;

    const float* cb = coords + (size_t)b * 3 * NPTS + n;
    float fx = fminf(fmaxf(cb[0]        * 32.0f, 0.0f), 31.0f);
    float fy = fminf(fmaxf(cb[NPTS]     * 32.0f, 0.0f), 31.0f);
    float fz = fminf(fmaxf(cb[2 * NPTS] * 32.0f, 0.0f), 31.0f);
    int x = (int)rintf(fx);
    int y = (int)rintf(fy);
    int z = (int)rintf(fz);
    uint32 g = (uint32)(b * R3 + x * (RR * RR) + y * RR + z);

    float* o2 = out2 + (size_t)b * 3 * NPTS + n;
    o2[0]        = (float)x;
    o2[NPTS]     = (float)y;
    o2[2 * NPTS] = (float)z;

    vox[gid] = g;
    atomicAdd(&cnt[g], 1u);
}

__global__ __launch_bounds__(256) void scan_block_sums(
    const uint32* __restrict__ cnt, uint32* __restrict__ bsum)
{
    __shared__ uint32 s[256];
    int t = threadIdx.x;
    s[t] = cnt[blockIdx.x * 256 + t];
    __syncthreads();
    for (int off = 128; off > 0; off >>= 1) {
        if (t < off) s[t] += s[t + off];
        __syncthreads();
    }
    if (t == 0) bsum[blockIdx.x] = s[0];
}

__global__ __launch_bounds__(256) void scan_final(
    const uint32* __restrict__ cnt, const uint32* __restrict__ bsum,
    uint32* __restrict__ starts, uint32* __restrict__ cursor)
{
    __shared__ uint32 s[256];
    int t = threadIdx.x;
    int gid = blockIdx.x * 256 + t;
    uint32 v = cnt[gid];
    s[t] = v;
    __syncthreads();
    for (int off = 1; off < 256; off <<= 1) {
        uint32 x = (t >= off) ? s[t - off] : 0u;
        __syncthreads();
        s[t] += x;
        __syncthreads();
    }
    uint32 st = bsum[blockIdx.x] + s[t] - v;
    starts[gid] = st;
    cursor[gid] = st;
}

__global__ __launch_bounds__(256) void phase3_scatter(
    const float* __restrict__ feat,
    const uint32* __restrict__ vox,
    uint32* __restrict__ cursor,
    uint4* __restrict__ sorted)
{
    int gid = blockIdx.x * blockDim.x + threadIdx.x;
    if (gid >= NPOINTS) return;
    int b = gid / NPTS;
    int n = gid - b * NPTS;

    uint32 g = vox[gid];
    uint32 pos = atomicAdd(&cursor[g], 1u);

    const float* frow = feat + (size_t)b * CH * NPTS + n;
    uint4* dst = sorted + (size_t)pos * 8;
#pragma unroll
    for (int j = 0; j < 8; ++j) {
        uint4 w;
        float f0 = frow[(size_t)(8 * j + 0) * NPTS];
        float f1 = frow[(size_t)(8 * j + 1) * NPTS];
        float f2 = frow[(size_t)(8 * j + 2) * NPTS];
        float f3 = frow[(size_t)(8 * j + 3) * NPTS];
        float f4 = frow[(size_t)(8 * j + 4) * NPTS];
        float f5 = frow[(size_t)(8 * j + 5) * NPTS];
        float f6 = frow[(size_t)(8 * j + 6) * NPTS];
        float f7 = frow[(size_t)(8 * j + 7) * NPTS];
        w.x = f2bf(f0) | (f2bf(f1) << 16);
        w.y = f2bf(f2) | (f2bf(f3) << 16);
        w.z = f2bf(f4) | (f2bf(f5) << 16);
        w.w = f2bf(f6) | (f2bf(f7) << 16);
        dst[j] = w;
    }
}

// ---------------------------------------------------------------------------
// Fallback path (tiny ws): direct atomic accumulate into d_out.
// ---------------------------------------------------------------------------
__global__ __launch_bounds__(256) void accum_direct(
    const float* __restrict__ feat, const float* __restrict__ coords,
    float* __restrict__ out1, uint32* __restrict__ cnt, float* __restrict__ out2)
{
    int gid = blockIdx.x * blockDim.x + threadIdx.x;
    if (gid >= NPOINTS) return;
    int b = gid / NPTS;
    int n = gid - b * NPTS;
    const float* cb = coords + (size_t)b * 3 * NPTS + n;
    float fx = fminf(fmaxf(cb[0]        * 32.0f, 0.0f), 31.0f);
    float fy = fminf(fmaxf(cb[NPTS]     * 32.0f, 0.0f), 31.0f);
    float fz = fminf(fmaxf(cb[2 * NPTS] * 32.0f, 0.0f), 31.0f);
    int x = (int)rintf(fx), y = (int)rintf(fy), z = (int)rintf(fz);
    int v = x * (RR * RR) + y * RR + z;
    float* o2 = out2 + (size_t)b * 3 * NPTS + n;
    o2[0] = (float)x; o2[NPTS] = (float)y; o2[2 * NPTS] = (float)z;
    atomicAdd(&cnt[b * R3 + v], 1u);
    float* obase = out1 + (size_t)(b * CH) * R3 + v;
    const float* frow = feat + (size_t)(b * CH) * NPTS + n;
#pragma unroll 8
    for (int c = 0; c < CH; ++c)
        unsafeAtomicAdd(&obase[(size_t)c * R3], frow[(size_t)c * NPTS]);
}

__global__ __launch_bounds__(256) void finalize_direct(
    float* __restrict__ out1, const uint32* __restrict__ cnt)
{
    size_t gid = (size_t)blockIdx.x * blockDim.x + threadIdx.x;
    size_t total = (size_t)BATCH * CH * R3;
    if (gid >= total) return;
    int v = (int)(gid & (R3 - 1));
    int b = (int)(gid / ((size_t)CH * R3));
    uint32 ct = cnt[b * R3 + v];
    out1[gid] = out1[gid] / (float)(ct > 1u ? ct : 1u);
}

// ---------------------------------------------------------------------------
extern "C" void kernel_launch(void* const* d_in, const int* in_sizes, int n_in,
                              void* d_out, int out_size, void* d_ws, size_t ws_size,
                              hipStream_t stream)
{
    const float* feat   = (const float*)d_in[0];   // [8, 64, 100000]
    const float* coords = (const float*)d_in[1];   // [8, 3, 100000]

    float* out1 = (float*)d_out;                          // [8, 64, 32768]
    float* out2 = out1 + (size_t)BATCH * CH * R3;         // [8, 3, 100000]

    // primary layout (rank path, atomic-free scatter)
    const size_t vox_off    = 0;
    const size_t vox_bytes  = (size_t)NPOINTS * 4;                 // 3.2 MB
    const size_t cnt_off    = vox_off + ((vox_bytes + 255) & ~255ull);
    const size_t cnt_bytes  = (size_t)NVOX * 4;                    // 1 MB
    const size_t starts_off = cnt_off + ((cnt_bytes + 255) & ~255ull);
    const size_t bsum_off   = starts_off + ((cnt_bytes + 255) & ~255ull);
    const size_t bsum_bytes = (size_t)SCAN_BLOCKS * 4;
    const size_t phist_off  = (bsum_off + bsum_bytes + 255) & ~255ull;
    const size_t phist_bytes= (size_t)BATCH * HBLK * R3 * 4;       // 8 MB
    const size_t sortA_off  = (phist_off + phist_bytes + 255) & ~255ull;
    const size_t sort_bytes = (size_t)NPOINTS * 128;               // 102.4 MB
    const size_t need_rank  = sortA_off + sort_bytes;              // ~115.8 MB

    // middle layout (R0 cursor path)
    const size_t cursor_off = bsum_off;                            // reuse slot
    const size_t bsumB_off  = cursor_off + ((cnt_bytes + 255) & ~255ull);
    const size_t sortB_off  = (bsumB_off + bsum_bytes + 255) & ~255ull;
    const size_t need_cur   = sortB_off + sort_bytes;              // ~108.8 MB

    const int npt_blocks = (NPOINTS + 255) / 256;   // 3125

    if (ws_size >= need_rank) {
        char* ws = (char*)d_ws;
        uint32* vox    = (uint32*)(ws + vox_off);
        uint32* cnt    = (uint32*)(ws + cnt_off);
        uint32* starts = (uint32*)(ws + starts_off);
        uint32* bsum   = (uint32*)(ws + bsum_off);
        uint32* phist  = (uint32*)(ws + phist_off);
        uint32* sorted = (uint32*)(ws + sortA_off);

        voxrank<<<BATCH * HBLK, 256, 0, stream>>>(coords, vox, phist, out2);
        scan_hist_sums<<<SCAN_BLOCKS, 256, 0, stream>>>(phist, cnt, bsum);
        scan_bsum<<<1, 256, 0, stream>>>(bsum);
        scan_starts<<<SCAN_BLOCKS, 256, 0, stream>>>(cnt, bsum, starts);
        make_pbase<<<SCAN_BLOCKS, 256, 0, stream>>>(phist, starts);
        scatter_rank<<<npt_blocks, 256, 0, stream>>>(feat, vox, phist, (uint4*)sorted);
        phase4_reduce<<<NVOX / 64, 256, 0, stream>>>(sorted, starts, out1);
    } else if (ws_size >= need_cur) {
        char* ws = (char*)d_ws;
        uint32* vox    = (uint32*)(ws + vox_off);
        uint32* cnt    = (uint32*)(ws + cnt_off);
        uint32* starts = (uint32*)(ws + starts_off);
        uint32* cursor = (uint32*)(ws + cursor_off);
        uint32* bsum   = (uint32*)(ws + bsumB_off);
        uint32* sorted = (uint32*)(ws + sortB_off);

        hipMemsetAsync(cnt, 0, cnt_bytes, stream);
        phase1_count<<<npt_blocks, 256, 0, stream>>>(coords, vox, cnt, out2);
        scan_block_sums<<<SCAN_BLOCKS, 256, 0, stream>>>(cnt, bsum);
        scan_bsum<<<1, 256, 0, stream>>>(bsum);
        scan_final<<<SCAN_BLOCKS, 256, 0, stream>>>(cnt, bsum, starts, cursor);
        phase3_scatter<<<npt_blocks, 256, 0, stream>>>(feat, vox, cursor, (uint4*)sorted);
        phase4_reduce<<<NVOX / 64, 256, 0, stream>>>(sorted, starts, out1);
    } else {
        // fallback: direct atomic accumulate into d_out
        uint32* cnt = (uint32*)d_ws;
        hipMemsetAsync(out1, 0, (size_t)BATCH * CH * R3 * sizeof(float), stream);
        hipMemsetAsync(d_ws, 0, (size_t)NVOX * 4, stream);
        accum_direct<<<npt_blocks, 256, 0, stream>>>(feat, coords, out1, cnt, out2);
        size_t total = (size_t)BATCH * CH * R3;
        finalize_direct<<<(unsigned)((total + 255) / 256), 256, 0, stream>>>(out1, cnt);
    }
}

// Round 6
// 408.352 us; speedup vs baseline: 1.1736x; 1.1736x over previous
//
#include <hip/hip_runtime.h>

#define RR 32
#define R3 32768
#define BATCH 8
#define CH 64
#define NPTS 100000
#define NPOINTS (BATCH * NPTS)   // 800000 (= 3125 * 256 exactly)
#define NVOX (BATCH * R3)        // 262144
#define SCAN_BLOCKS (NVOX / 256) // 1024
#define HBLK 16                  // histogram blocks per batch
#define PPB (NPTS / HBLK)        // 6250 points per hist block (rank < 2^16)

typedef unsigned int uint32;

__device__ __forceinline__ uint32 f2bf(float f) {
    uint32 u = __float_as_uint(f);
    return (u + 0x7fffu + ((u >> 16) & 1u)) >> 16;   // RNE to bf16
}
__device__ __forceinline__ float bf2f(uint32 h) {
    return __uint_as_float(h << 16);
}

// ---------------------------------------------------------------------------
// K1: voxelize + LDS hist; ds-atomic RETURN = stable local rank.
// vox[gid] = v | (rank << 16). Partial counts -> phist. 128 blocks, 512 thr.
// ---------------------------------------------------------------------------
__global__ __launch_bounds__(512) void voxrank(
    const float* __restrict__ coords,  // [B, 3, N]
    uint32* __restrict__ vox,          // [NPOINTS] packed v | rank<<16
    uint32* __restrict__ phist,        // [B*HBLK][R3] partial histograms
    float* __restrict__ out2)          // [B, 3, N] voxel coords as float
{
    __shared__ uint32 hist[R3];        // 128 KiB

    int b   = blockIdx.x >> 4;         // 0..7
    int blk = blockIdx.x & 15;         // 0..15
    int tid = threadIdx.x;

    uint4 z4 = make_uint4(0u, 0u, 0u, 0u);
    for (int i = tid; i < R3 / 4; i += 512) ((uint4*)hist)[i] = z4;
    __syncthreads();

    int n0 = blk * PPB;
    const float* cb = coords + (size_t)b * 3 * NPTS;
    float*       o2 = out2   + (size_t)b * 3 * NPTS;

    for (int i = tid; i < PPB; i += 512) {
        int n = n0 + i;
        float fx = fminf(fmaxf(cb[n]            * 32.0f, 0.0f), 31.0f);
        float fy = fminf(fmaxf(cb[NPTS + n]     * 32.0f, 0.0f), 31.0f);
        float fz = fminf(fmaxf(cb[2 * NPTS + n] * 32.0f, 0.0f), 31.0f);
        int x = (int)rintf(fx);   // round-half-even matches jnp.round
        int y = (int)rintf(fy);
        int z = (int)rintf(fz);
        int v = x * (RR * RR) + y * RR + z;

        o2[n]            = (float)x;
        o2[NPTS + n]     = (float)y;
        o2[2 * NPTS + n] = (float)z;

        uint32 r = atomicAdd(&hist[v], 1u);           // ds_add_rtn, local rank
        vox[(size_t)b * NPTS + n] = (uint32)v | (r << 16);
    }
    __syncthreads();

    uint4* ph = (uint4*)(phist + (size_t)(b * HBLK + blk) * R3);
    for (int i = tid; i < R3 / 4; i += 512) ph[i] = ((const uint4*)hist)[i];
}

// ---------------------------------------------------------------------------
// K2: sum the HBLK partial histograms per voxel -> cnt, plus block sums.
// ---------------------------------------------------------------------------
__global__ __launch_bounds__(256) void scan_hist_sums(
    const uint32* __restrict__ phist,
    uint32* __restrict__ cnt, uint32* __restrict__ bsum)
{
    __shared__ uint32 s[256];
    int t = threadIdx.x;
    int gid = blockIdx.x * 256 + t;
    int b = gid >> 15;                 // gid / R3
    int v = gid & (R3 - 1);

    const uint32* ph = phist + (size_t)b * HBLK * R3 + v;
    uint32 c = 0;
#pragma unroll
    for (int k = 0; k < HBLK; ++k) c += ph[(size_t)k * R3];
    cnt[gid] = c;

    s[t] = c;
    __syncthreads();
    for (int off = 128; off > 0; off >>= 1) {
        if (t < off) s[t] += s[t + off];
        __syncthreads();
    }
    if (t == 0) bsum[blockIdx.x] = s[0];
}

// ---------------------------------------------------------------------------
// K3: scan over the 1024 block sums (single block).
// ---------------------------------------------------------------------------
__global__ __launch_bounds__(256) void scan_bsum(uint32* __restrict__ bsum)
{
    __shared__ uint32 s[256];
    int t = threadIdx.x;
    uint32 v0 = bsum[4 * t], v1 = bsum[4 * t + 1], v2 = bsum[4 * t + 2], v3 = bsum[4 * t + 3];
    uint32 tot = v0 + v1 + v2 + v3;
    s[t] = tot;
    __syncthreads();
    for (int off = 1; off < 256; off <<= 1) {
        uint32 x = (t >= off) ? s[t - off] : 0u;
        __syncthreads();
        s[t] += x;
        __syncthreads();
    }
    uint32 excl = s[t] - tot;
    bsum[4 * t]     = excl;
    bsum[4 * t + 1] = excl + v0;
    bsum[4 * t + 2] = excl + v0 + v1;
    bsum[4 * t + 3] = excl + v0 + v1 + v2;
}

// ---------------------------------------------------------------------------
// K4: exclusive scan -> starts only (scatter is atomic-free).
// ---------------------------------------------------------------------------
__global__ __launch_bounds__(256) void scan_starts(
    const uint32* __restrict__ cnt, const uint32* __restrict__ bsum,
    uint32* __restrict__ starts)
{
    __shared__ uint32 s[256];
    int t = threadIdx.x;
    int gid = blockIdx.x * 256 + t;
    uint32 v = cnt[gid];
    s[t] = v;
    __syncthreads();
    for (int off = 1; off < 256; off <<= 1) {
        uint32 x = (t >= off) ? s[t - off] : 0u;
        __syncthreads();
        s[t] += x;
        __syncthreads();
    }
    starts[gid] = bsum[blockIdx.x] + s[t] - v;   // exclusive
}

// ---------------------------------------------------------------------------
// K5: partial counts -> per-(block,voxel) BASES, in place.
// ---------------------------------------------------------------------------
__global__ __launch_bounds__(256) void make_pbase(
    uint32* __restrict__ phist,        // in: counts, out: bases
    const uint32* __restrict__ starts)
{
    int gid = blockIdx.x * 256 + threadIdx.x;   // over NVOX
    int b = gid >> 15;
    int v = gid & (R3 - 1);
    uint32 s = starts[gid];
    uint32* ph = phist + (size_t)b * HBLK * R3 + v;
#pragma unroll
    for (int k = 0; k < HBLK; ++k) {
        uint32 c = ph[(size_t)k * R3];
        ph[(size_t)k * R3] = s;
        s += c;
    }
}

// ---------------------------------------------------------------------------
// K6: FULL-LINE scatter. Stage 256 points' bf16 rows in LDS, then write each
// point's 128 B with 8 lanes x 16 B in ONE instruction-group (8 points per
// wave-instr) -> every sorted line committed whole, no partial sectors.
// ---------------------------------------------------------------------------
__global__ __launch_bounds__(256) void scatter_line(
    const float* __restrict__ feat,    // [B, C, N]
    const uint32* __restrict__ vox,    // packed v | rank<<16
    const uint32* __restrict__ pbase,  // [B*HBLK][R3] bases
    uint4* __restrict__ sorted)        // [NPOINTS][8] uint4 (= 64 bf16 ch)
{
    __shared__ uint32 buf[256 * 33];   // 33-word row stride: <=2-way banks
    __shared__ uint32 posb[256];

    int tid = threadIdx.x;
    int gid = blockIdx.x * 256 + tid;  // NPOINTS % 256 == 0
    int b = gid / NPTS;
    int n = gid - b * NPTS;

    uint32 vr = vox[gid];
    uint32 v  = vr & 0xffffu;
    uint32 r  = vr >> 16;
    int   blk = n / PPB;               // 0..15, ~constant per block -> L2-local
    posb[tid] = pbase[(size_t)(b * HBLK + blk) * R3 + v] + r;

    const float* frow = feat + (size_t)b * CH * NPTS + n;
#pragma unroll
    for (int j = 0; j < 8; ++j) {
        uint4 w;
        float f0 = frow[(size_t)(8 * j + 0) * NPTS];
        float f1 = frow[(size_t)(8 * j + 1) * NPTS];
        float f2 = frow[(size_t)(8 * j + 2) * NPTS];
        float f3 = frow[(size_t)(8 * j + 3) * NPTS];
        float f4 = frow[(size_t)(8 * j + 4) * NPTS];
        float f5 = frow[(size_t)(8 * j + 5) * NPTS];
        float f6 = frow[(size_t)(8 * j + 6) * NPTS];
        float f7 = frow[(size_t)(8 * j + 7) * NPTS];
        w.x = f2bf(f0) | (f2bf(f1) << 16);
        w.y = f2bf(f2) | (f2bf(f3) << 16);
        w.z = f2bf(f4) | (f2bf(f5) << 16);
        w.w = f2bf(f6) | (f2bf(f7) << 16);
        *(uint4*)&buf[tid * 33 + j * 4] = w;
    }
    __syncthreads();

#pragma unroll
    for (int rep = 0; rep < 8; ++rep) {
        int p  = rep * 32 + (tid >> 3);          // 8 lanes per point
        int li = tid & 7;
        uint4  w   = *(const uint4*)&buf[p * 33 + li * 4];
        uint32 pos = posb[p];                    // LDS broadcast
        sorted[(size_t)pos * 8 + li] = w;        // 8x16B = full 128-B line
    }
}

// ---------------------------------------------------------------------------
// K7: per-block reduce of 64 consecutive voxels, FULL-wave (R3-verified).
// ---------------------------------------------------------------------------
__global__ __launch_bounds__(256) void phase4_reduce(
    const uint32* __restrict__ sorted,   // [NPOINTS][32] uint (bf16x2)
    const uint32* __restrict__ starts,
    float* __restrict__ out1)            // [B, C, R3]
{
    __shared__ float tile[64][65];

    int gbase = blockIdx.x * 64;       // global voxel base
    int tid = threadIdx.x;
    int w = tid >> 6, lane = tid & 63;
    int half = lane >> 5;              // 0: even points, 1: odd points
    int cp   = lane & 31;              // channel-pair index

    for (int k = 0; k < 16; ++k) {
        int g = gbase + w * 16 + k;
        uint32 s = starts[g];
        uint32 e = (g == NVOX - 1) ? (uint32)NPOINTS : starts[g + 1];
        float a0 = 0.0f, a1 = 0.0f;
        for (uint32 p = s + half; p < e; p += 2) {
            uint32 d = sorted[(size_t)p * 32 + cp];
            a0 += bf2f(d & 0xffffu);
            a1 += bf2f(d >> 16);
        }
        a0 += __shfl_xor(a0, 32);
        a1 += __shfl_xor(a1, 32);
        if (half == 0) {
            uint32 c = e - s;
            float rcp = 1.0f / (float)(c > 1u ? c : 1u);
            int vloc = w * 16 + k;
            tile[vloc][2 * cp]     = a0 * rcp;
            tile[vloc][2 * cp + 1] = a1 * rcp;
        }
    }
    __syncthreads();

    int b = gbase / R3;
    int v0 = gbase - b * R3;
    int vv = tid & 63;
    int c0 = tid >> 6;
    float* obase = out1 + (size_t)b * CH * R3 + v0 + vv;
#pragma unroll
    for (int jj = 0; jj < 16; ++jj) {
        int c = jj * 4 + c0;
        obase[(size_t)c * R3] = tile[vv][c];
    }
}

// ---------------------------------------------------------------------------
// Middle path (ws fits R0 layout but not phist): R0-proven cursor pipeline.
// ---------------------------------------------------------------------------
__global__ __launch_bounds__(256) void phase1_count(
    const float* __restrict__ coords,
    uint32* __restrict__ vox,          // GLOBAL voxel id
    uint32* __restrict__ cnt,          // pre-zeroed
    float* __restrict__ out2)
{
    int gid = blockIdx.x * blockDim.x + threadIdx.x;
    if (gid >= NPOINTS) return;
    int b = gid / NPTS;
    int n = gid - b * NPTS;

    const float* cb = coords + (size_t)b * 3 * NPTS + n;
    float fx = fminf(fmaxf(cb[0]        * 32.0f, 0.0f), 31.0f);
    float fy = fminf(fmaxf(cb[NPTS]     * 32.0f, 0.0f), 31.0f);
    float fz = fminf(fmaxf(cb[2 * NPTS] * 32.0f, 0.0f), 31.0f);
    int x = (int)rintf(fx);
    int y = (int)rintf(fy);
    int z = (int)rintf(fz);
    uint32 g = (uint32)(b * R3 + x * (RR * RR) + y * RR + z);

    float* o2 = out2 + (size_t)b * 3 * NPTS + n;
    o2[0]        = (float)x;
    o2[NPTS]     = (float)y;
    o2[2 * NPTS] = (float)z;

    vox[gid] = g;
    atomicAdd(&cnt[g], 1u);
}

__global__ __launch_bounds__(256) void scan_block_sums(
    const uint32* __restrict__ cnt, uint32* __restrict__ bsum)
{
    __shared__ uint32 s[256];
    int t = threadIdx.x;
    s[t] = cnt[blockIdx.x * 256 + t];
    __syncthreads();
    for (int off = 128; off > 0; off >>= 1) {
        if (t < off) s[t] += s[t + off];
        __syncthreads();
    }
    if (t == 0) bsum[blockIdx.x] = s[0];
}

__global__ __launch_bounds__(256) void scan_final(
    const uint32* __restrict__ cnt, const uint32* __restrict__ bsum,
    uint32* __restrict__ starts, uint32* __restrict__ cursor)
{
    __shared__ uint32 s[256];
    int t = threadIdx.x;
    int gid = blockIdx.x * 256 + t;
    uint32 v = cnt[gid];
    s[t] = v;
    __syncthreads();
    for (int off = 1; off < 256; off <<= 1) {
        uint32 x = (t >= off) ? s[t - off] : 0u;
        __syncthreads();
        s[t] += x;
        __syncthreads();
    }
    uint32 st = bsum[blockIdx.x] + s[t] - v;
    starts[gid] = st;
    cursor[gid] = st;
}

__global__ __launch_bounds__(256) void phase3_scatter(
    const float* __restrict__ feat,
    const uint32* __restrict__ vox,
    uint32* __restrict__ cursor,
    uint4* __restrict__ sorted)
{
    int gid = blockIdx.x * blockDim.x + threadIdx.x;
    if (gid >= NPOINTS) return;
    int b = gid / NPTS;
    int n = gid - b * NPTS;

    uint32 g = vox[gid];
    uint32 pos = atomicAdd(&cursor[g], 1u);

    const float* frow = feat + (size_t)b * CH * NPTS + n;
    uint4* dst = sorted + (size_t)pos * 8;
#pragma unroll
    for (int j = 0; j < 8; ++j) {
        uint4 w;
        float f0 = frow[(size_t)(8 * j + 0) * NPTS];
        float f1 = frow[(size_t)(8 * j + 1) * NPTS];
        float f2 = frow[(size_t)(8 * j + 2) * NPTS];
        float f3 = frow[(size_t)(8 * j + 3) * NPTS];
        float f4 = frow[(size_t)(8 * j + 4) * NPTS];
        float f5 = frow[(size_t)(8 * j + 5) * NPTS];
        float f6 = frow[(size_t)(8 * j + 6) * NPTS];
        float f7 = frow[(size_t)(8 * j + 7) * NPTS];
        w.x = f2bf(f0) | (f2bf(f1) << 16);
        w.y = f2bf(f2) | (f2bf(f3) << 16);
        w.z = f2bf(f4) | (f2bf(f5) << 16);
        w.w = f2bf(f6) | (f2bf(f7) << 16);
        dst[j] = w;
    }
}

// ---------------------------------------------------------------------------
// Fallback path (tiny ws): direct atomic accumulate into d_out.
// ---------------------------------------------------------------------------
__global__ __launch_bounds__(256) void accum_direct(
    const float* __restrict__ feat, const float* __restrict__ coords,
    float* __restrict__ out1, uint32* __restrict__ cnt, float* __restrict__ out2)
{
    int gid = blockIdx.x * blockDim.x + threadIdx.x;
    if (gid >= NPOINTS) return;
    int b = gid / NPTS;
    int n = gid - b * NPTS;
    const float* cb = coords + (size_t)b * 3 * NPTS + n;
    float fx = fminf(fmaxf(cb[0]        * 32.0f, 0.0f), 31.0f);
    float fy = fminf(fmaxf(cb[NPTS]     * 32.0f, 0.0f), 31.0f);
    float fz = fminf(fmaxf(cb[2 * NPTS] * 32.0f, 0.0f), 31.0f);
    int x = (int)rintf(fx), y = (int)rintf(fy), z = (int)rintf(fz);
    int v = x * (RR * RR) + y * RR + z;
    float* o2 = out2 + (size_t)b * 3 * NPTS + n;
    o2[0] = (float)x; o2[NPTS] = (float)y; o2[2 * NPTS] = (float)z;
    atomicAdd(&cnt[b * R3 + v], 1u);
    float* obase = out1 + (size_t)(b * CH) * R3 + v;
    const float* frow = feat + (size_t)(b * CH) * NPTS + n;
#pragma unroll 8
    for (int c = 0; c < CH; ++c)
        unsafeAtomicAdd(&obase[(size_t)c * R3], frow[(size_t)c * NPTS]);
}

__global__ __launch_bounds__(256) void finalize_direct(
    float* __restrict__ out1, const uint32* __restrict__ cnt)
{
    size_t gid = (size_t)blockIdx.x * blockDim.x + threadIdx.x;
    size_t total = (size_t)BATCH * CH * R3;
    if (gid >= total) return;
    int v = (int)(gid & (R3 - 1));
    int b = (int)(gid / ((size_t)CH * R3));
    uint32 ct = cnt[b * R3 + v];
    out1[gid] = out1[gid] / (float)(ct > 1u ? ct : 1u);
}

// ---------------------------------------------------------------------------
extern "C" void kernel_launch(void* const* d_in, const int* in_sizes, int n_in,
                              void* d_out, int out_size, void* d_ws, size_t ws_size,
                              hipStream_t stream)
{
    const float* feat   = (const float*)d_in[0];   // [8, 64, 100000]
    const float* coords = (const float*)d_in[1];   // [8, 3, 100000]

    float* out1 = (float*)d_out;                          // [8, 64, 32768]
    float* out2 = out1 + (size_t)BATCH * CH * R3;         // [8, 3, 100000]

    // primary layout (rank path, atomic-free full-line scatter)
    const size_t vox_off    = 0;
    const size_t vox_bytes  = (size_t)NPOINTS * 4;                 // 3.2 MB
    const size_t cnt_off    = vox_off + ((vox_bytes + 255) & ~255ull);
    const size_t cnt_bytes  = (size_t)NVOX * 4;                    // 1 MB
    const size_t starts_off = cnt_off + ((cnt_bytes + 255) & ~255ull);
    const size_t bsum_off   = starts_off + ((cnt_bytes + 255) & ~255ull);
    const size_t bsum_bytes = (size_t)SCAN_BLOCKS * 4;
    const size_t phist_off  = (bsum_off + bsum_bytes + 255) & ~255ull;
    const size_t phist_bytes= (size_t)BATCH * HBLK * R3 * 4;       // 16.8 MB
    const size_t sortA_off  = (phist_off + phist_bytes + 255) & ~255ull;
    const size_t sort_bytes = (size_t)NPOINTS * 128;               // 102.4 MB
    const size_t need_rank  = sortA_off + sort_bytes;              // ~124.6 MB

    // middle layout (R0 cursor path)
    const size_t cursor_off = bsum_off;                            // reuse slot
    const size_t bsumB_off  = cursor_off + ((cnt_bytes + 255) & ~255ull);
    const size_t sortB_off  = (bsumB_off + bsum_bytes + 255) & ~255ull;
    const size_t need_cur   = sortB_off + sort_bytes;              // ~108.8 MB

    const int npt_blocks = (NPOINTS + 255) / 256;   // 3125

    if (ws_size >= need_rank) {
        char* ws = (char*)d_ws;
        uint32* vox    = (uint32*)(ws + vox_off);
        uint32* cnt    = (uint32*)(ws + cnt_off);
        uint32* starts = (uint32*)(ws + starts_off);
        uint32* bsum   = (uint32*)(ws + bsum_off);
        uint32* phist  = (uint32*)(ws + phist_off);
        uint32* sorted = (uint32*)(ws + sortA_off);

        voxrank<<<BATCH * HBLK, 512, 0, stream>>>(coords, vox, phist, out2);
        scan_hist_sums<<<SCAN_BLOCKS, 256, 0, stream>>>(phist, cnt, bsum);
        scan_bsum<<<1, 256, 0, stream>>>(bsum);
        scan_starts<<<SCAN_BLOCKS, 256, 0, stream>>>(cnt, bsum, starts);
        make_pbase<<<SCAN_BLOCKS, 256, 0, stream>>>(phist, starts);
        scatter_line<<<npt_blocks, 256, 0, stream>>>(feat, vox, phist, (uint4*)sorted);
        phase4_reduce<<<NVOX / 64, 256, 0, stream>>>(sorted, starts, out1);
    } else if (ws_size >= need_cur) {
        char* ws = (char*)d_ws;
        uint32* vox    = (uint32*)(ws + vox_off);
        uint32* cnt    = (uint32*)(ws + cnt_off);
        uint32* starts = (uint32*)(ws + starts_off);
        uint32* cursor = (uint32*)(ws + cursor_off);
        uint32* bsum   = (uint32*)(ws + bsumB_off);
        uint32* sorted = (uint32*)(ws + sortB_off);

        hipMemsetAsync(cnt, 0, cnt_bytes, stream);
        phase1_count<<<npt_blocks, 256, 0, stream>>>(coords, vox, cnt, out2);
        scan_block_sums<<<SCAN_BLOCKS, 256, 0, stream>>>(cnt, bsum);
        scan_bsum<<<1, 256, 0, stream>>>(bsum);
        scan_final<<<SCAN_BLOCKS, 256, 0, stream>>>(cnt, bsum, starts, cursor);
        phase3_scatter<<<npt_blocks, 256, 0, stream>>>(feat, vox, cursor, (uint4*)sorted);
        phase4_reduce<<<NVOX / 64, 256, 0, stream>>>(sorted, starts, out1);
    } else {
        // fallback: direct atomic accumulate into d_out
        uint32* cnt = (uint32*)d_ws;
        hipMemsetAsync(out1, 0, (size_t)BATCH * CH * R3 * sizeof(float), stream);
        hipMemsetAsync(d_ws, 0, (size_t)NVOX * 4, stream);
        accum_direct<<<npt_blocks, 256, 0, stream>>>(feat, coords, out1, cnt, out2);
        size_t total = (size_t)BATCH * CH * R3;
        finalize_direct<<<(unsigned)((total + 255) / 256), 256, 0, stream>>>(out1, cnt);
    }
}